// Round 1
// 375.023 us; speedup vs baseline: 1.1377x; 1.1377x over previous
//
#include <hip/hip_runtime.h>
#include <hip/hip_bf16.h>
#include <math.h>

typedef __hip_bfloat16 bf16;
typedef short s8v __attribute__((ext_vector_type(8)));
typedef short s4v __attribute__((ext_vector_type(4)));
typedef float f4v __attribute__((ext_vector_type(4)));

__device__ __forceinline__ float b2f(bf16 x) { return __bfloat162float(x); }
__device__ __forceinline__ bf16 f2b(float x) { return __float2bfloat16(x); }
__device__ __forceinline__ f4v mfma16(s8v a, s8v b, f4v c) {
    return __builtin_amdgcn_mfma_f32_16x16x32_bf16(a, b, c, 0, 0, 0);
}
__device__ __forceinline__ void async16(const bf16* g, bf16* l) {
    __builtin_amdgcn_global_load_lds(
        (const __attribute__((address_space(1))) void*)g,
        (__attribute__((address_space(3))) void*)l, 16, 0, 0);
}

constexpr int Bn = 4, Tn = 2048, Dn = 1024, KDn = 512, VDn = 1024;
constexpr int Hn = 4, Mn = 64, HKn = 128, HVn = 256;
constexpr int BT = Bn * Tn;

// ---------------------------------------------------------------------------
__global__ __launch_bounds__(256) void probe_dtype_kernel(
    const void* __restrict__ x, int* __restrict__ flag)
{
    const bf16* xb = (const bf16*)x;
    float mx = 0.f;
    for (int i = threadIdx.x; i < 4096; i += 256) {
        float v = fabsf(b2f(xb[i]));
        if (isnan(v)) v = 1e30f;
        mx = fmaxf(mx, v);
    }
    __shared__ float red[256];
    red[threadIdx.x] = mx;
    __syncthreads();
    for (int s = 128; s > 0; s >>= 1) {
        if (threadIdx.x < s) red[threadIdx.x] = fmaxf(red[threadIdx.x], red[threadIdx.x + s]);
        __syncthreads();
    }
    if (threadIdx.x == 0) flag[0] = (red[0] > 1e6f) ? 1 : 0;
}

__global__ __launch_bounds__(256) void convert_kernel(
    const void* __restrict__ src, bf16* __restrict__ dst,
    const int* __restrict__ flag, int n)
{
    int is32 = flag[0];
    int i0 = (blockIdx.x * 256 + threadIdx.x) * 4;
#pragma unroll
    for (int j = 0; j < 4; j++) {
        int i = i0 + j;
        if (i < n)
            dst[i] = is32 ? f2b(((const float*)src)[i]) : ((const bf16*)src)[i];
    }
}

__global__ __launch_bounds__(256) void convert_small_kernel(
    const void* __restrict__ q, const void* __restrict__ k,
    const void* __restrict__ v, const void* __restrict__ g,
    bf16* __restrict__ qd, bf16* __restrict__ kd,
    bf16* __restrict__ vd, bf16* __restrict__ gd,
    const int* __restrict__ flag)
{
    int is32 = flag[0];
    for (int i = threadIdx.x; i < 8448; i += 256) {
        const void* s; bf16* d; int l;
        if (i < 2048)      { s = q; d = qd; l = i; }
        else if (i < 4096) { s = k; d = kd; l = i - 2048; }
        else if (i < 8192) { s = v; d = vd; l = i - 4096; }
        else               { s = g; d = gd; l = i - 8192; }
        d[l] = is32 ? f2b(((const float*)s)[l]) : ((const bf16*)s)[l];
    }
}

__global__ __launch_bounds__(256) void convert_t6_kernel(
    const void* s0, const void* s1, const void* s2, const void* s3,
    const void* s4, const void* s5,
    bf16* d0, bf16* d1, bf16* d2, bf16* d3, bf16* d4, bf16* d5,
    const int* __restrict__ flag)
{
    __shared__ bf16 tile[64 * 72];
    int is32 = flag[0];
    int nb = blockIdx.x;
    const void* src; bf16* dst; int K, N, loc;
    if (nb < 128)       { src = s0; dst = d0; K = 1024; N = 512;  loc = nb; }
    else if (nb < 256)  { src = s1; dst = d1; K = 1024; N = 512;  loc = nb - 128; }
    else if (nb < 512)  { src = s2; dst = d2; K = 1024; N = 1024; loc = nb - 256; }
    else if (nb < 576)  { src = s3; dst = d3; K = 1024; N = 256;  loc = nb - 512; }
    else if (nb < 832)  { src = s4; dst = d4; K = 1024; N = 1024; loc = nb - 576; }
    else                { src = s5; dst = d5; K = 1024; N = 1024; loc = nb - 832; }
    int nt = N >> 6;
    int n0 = (loc % nt) * 64, k0 = (loc / nt) * 64;
    int tid = threadIdx.x;
    int r = tid >> 2, seg = (tid & 3) * 16;
#pragma unroll
    for (int i = 0; i < 16; i++) {
        size_t gi = (size_t)(k0 + r) * N + n0 + seg + i;
        float v = is32 ? ((const float*)src)[gi] : b2f(((const bf16*)src)[gi]);
        tile[r * 72 + seg + i] = f2b(v);
    }
    __syncthreads();
    bf16 tmp[16];
#pragma unroll
    for (int i = 0; i < 16; i++) tmp[i] = tile[(seg + i) * 72 + r];
    size_t o = (size_t)(n0 + r) * K + k0 + seg;
    *(s8v*)&dst[o] = *(s8v*)&tmp[0];
    *(s8v*)&dst[o + 8] = *(s8v*)&tmp[8];
}

// ---------------------------------------------------------------------------
// MFMA GEMM (m97 recipe). EP 3 = dynamic fp32/bf16 per flag (final proj).
// ---------------------------------------------------------------------------
template <int EP>
__global__ __launch_bounds__(256) void gemm_mfma(
    const bf16* __restrict__ A, const bf16* __restrict__ BTm,
    void* __restrict__ Cout, bf16* __restrict__ Cout2,
    bf16* __restrict__ aux1, bf16* __restrict__ aux2,
    const int* __restrict__ flag, int M, int N, int K)
{
    __shared__ bf16 Xs[128 * 64];
    __shared__ bf16 Ws2[128 * 64];
    const int tid = threadIdx.x;
    const int w = tid >> 6, lane = tid & 63;
    const int l16 = lane & 15, q = lane >> 4;
    const int wr = w >> 1, wc = w & 1;
    const int m0 = blockIdx.y * 128, n0 = blockIdx.x * 128;
    int dyn = 0;
    if (EP == 3) dyn = flag[0];

    const int srow = w * 32 + (lane >> 3);
    const int scol = (lane & 7) * 8;
    const bf16* ga = A + (size_t)(m0 + srow) * K + scol;
    const bf16* gb = BTm + (size_t)(n0 + srow) * K + scol;

    f4v acc[4][4];
    f4v z = {0.f, 0.f, 0.f, 0.f};
#pragma unroll
    for (int i = 0; i < 4; i++)
#pragma unroll
        for (int j = 0; j < 4; j++) acc[i][j] = z;

    for (int k0 = 0; k0 < K; k0 += 64) {
#pragma unroll
        for (int c = 0; c < 4; c++) {
            async16(ga + (size_t)(c * 8) * K + k0, &Xs[(w * 32 + c * 8) * 64]);
            async16(gb + (size_t)(c * 8) * K + k0, &Ws2[(w * 32 + c * 8) * 64]);
        }
        __syncthreads();
#pragma unroll
        for (int kq = 0; kq < 2; kq++) {
            s8v a[4], b[4];
#pragma unroll
            for (int mi = 0; mi < 4; mi++)
                a[mi] = *(s8v*)&Xs[(wr * 64 + mi * 16 + l16) * 64 + kq * 32 + q * 8];
#pragma unroll
            for (int ni = 0; ni < 4; ni++)
                b[ni] = *(s8v*)&Ws2[(wc * 64 + ni * 16 + l16) * 64 + kq * 32 + q * 8];
#pragma unroll
            for (int mi = 0; mi < 4; mi++)
#pragma unroll
                for (int ni = 0; ni < 4; ni++)
                    acc[mi][ni] = mfma16(a[mi], b[ni], acc[mi][ni]);
        }
        __syncthreads();
    }
#pragma unroll
    for (int mi = 0; mi < 4; mi++)
#pragma unroll
        for (int ni = 0; ni < 4; ni++)
#pragma unroll
            for (int r = 0; r < 4; r++) {
                int row = m0 + wr * 64 + mi * 16 + q * 4 + r;
                int col = n0 + wc * 64 + ni * 16 + l16;
                float v = acc[mi][ni][r];
                size_t idx = (size_t)row * N + col;
                if (dyn) ((float*)Cout)[idx] = v;
                else ((bf16*)Cout)[idx] = f2b(v);
            }
}

// ---------------------------------------------------------------------------
// Merged projection GEMM, 256x256 tile, BK=32, 4-deep LDS ring, counted
// vmcnt(8) (never 0 in main loop), XOR-swizzled LDS, setprio, XCD swizzle.
// Grid: 416 blocks (13 bx * 32 by), 512 threads (8 waves, 2M x 4N).
// Epilogue regions (by bx): [0,4) qkpre, [4,8) gate, [8,12) vpre,
// 12 -> ET transposed with exp(clip()).
// ---------------------------------------------------------------------------
__global__ __launch_bounds__(512, 2) void gemm256_mproj(
    const bf16* __restrict__ A, const bf16* __restrict__ Bt,
    bf16* __restrict__ qkpre, bf16* __restrict__ ETout,
    bf16* __restrict__ gate, bf16* __restrict__ vpre)
{
    // 4 buffers x (A 256x32 + B 256x32) bf16 = 128 KiB
    __shared__ bf16 lds[4 * 16384];
    constexpr int K = 1024, GBK = 32, NKT = 32;
    const int tid = threadIdx.x;
    const int w8 = tid >> 6, lane = tid & 63;
    const int l16 = lane & 15, q2 = lane >> 4;
    const int wr = w8 >> 2, wc = w8 & 3;

    // XCD swizzle: 416 = 8 * 52 exactly (bijective). bx fastest within chunk.
    const int bid = blockIdx.x;
    const int wg = (bid & 7) * 52 + (bid >> 3);
    const int by = wg / 13, bx = wg - by * 13;

    // ---- staging addresses: 2 A-instr + 2 B-instr per thread per K-tile.
    // instr i covers 16 rows starting (w8*2+i)*16; lane -> (row=lane>>2,
    // physical 16B slot t=lane&3). Pre-swizzle global source so that the
    // linear gload_lds write realizes the XOR-swizzled layout (rule #21).
    const int sr0 = (w8 * 2 + 0) * 16 + (lane >> 2);
    const int sr1 = (w8 * 2 + 1) * 16 + (lane >> 2);
    const int sp = lane & 3;
    const int sw0 = (sr0 ^ (sr0 >> 2)) & 3;
    const int sw1 = (sr1 ^ (sr1 >> 2)) & 3;
    const bf16* gA0 = A + (size_t)(by * 256 + sr0) * K + (sp ^ sw0) * 8;
    const bf16* gA1 = A + (size_t)(by * 256 + sr1) * K + (sp ^ sw1) * 8;
    const bf16* gB0 = Bt + (size_t)(bx * 256 + sr0) * K + (sp ^ sw0) * 8;
    const bf16* gB1 = Bt + (size_t)(bx * 256 + sr1) * K + (sp ^ sw1) * 8;
    const int ldsA0 = (w8 * 2 + 0) * 512;   // elem offset of chunk (wave-uniform)
    const int ldsA1 = (w8 * 2 + 1) * 512;

    // ---- ds_read offsets (same swizzle on the read side)
    int aoff[8], boff[4];
#pragma unroll
    for (int mi = 0; mi < 8; ++mi) {
        int ra = wr * 128 + mi * 16 + l16;
        aoff[mi] = ra * 32 + ((q2 ^ ((ra ^ (ra >> 2)) & 3)) * 8);
    }
#pragma unroll
    for (int ni = 0; ni < 4; ++ni) {
        int rb = wc * 64 + ni * 16 + l16;
        boff[ni] = 8192 + rb * 32 + ((q2 ^ ((rb ^ (rb >> 2)) & 3)) * 8);
    }

    f4v acc[8][4];
    f4v z = {0.f, 0.f, 0.f, 0.f};
#pragma unroll
    for (int i = 0; i < 8; i++)
#pragma unroll
        for (int j = 0; j < 4; j++) acc[i][j] = z;

    // prologue: stage K-tiles 0..2 into buffers 0..2 (12 loads/thread)
    for (int t = 0; t < 3; ++t) {
        const size_t kb = (size_t)t * GBK;
        bf16* lb = &lds[t * 16384];
        async16(gA0 + kb, lb + ldsA0);
        async16(gA1 + kb, lb + ldsA1);
        async16(gB0 + kb, lb + 8192 + ldsA0);
        async16(gB1 + kb, lb + 8192 + ldsA1);
    }

#pragma unroll 4
    for (int w = 0; w < NKT; ++w) {
        // tile w landed (own 4 loads forced complete; tiles w+1,w+2 in flight)
        asm volatile("s_waitcnt vmcnt(8)" ::: "memory");
        __builtin_amdgcn_s_barrier();     // all waves: tile w landed,
        asm volatile("" ::: "memory");    // tile w-1 reads done -> buf free
        const bf16* lb = &lds[(w & 3) * 16384];
        int st = w + 3; if (st > NKT - 1) st = NKT - 1;   // clamp (junk re-stage)
        bf16* sb = &lds[((w + 3) & 3) * 16384];
        const size_t kb = (size_t)st * GBK;

        s8v a[4], b[4];
        // ---- phase 1: read a0-3, b0-3; issue A-stage; MFMA m0-3 x n0-3
#pragma unroll
        for (int mi = 0; mi < 4; ++mi) a[mi] = *(const s8v*)(lb + aoff[mi]);
#pragma unroll
        for (int ni = 0; ni < 4; ++ni) b[ni] = *(const s8v*)(lb + boff[ni]);
        async16(gA0 + kb, sb + ldsA0);
        async16(gA1 + kb, sb + ldsA1);
        __builtin_amdgcn_s_setprio(1);
#pragma unroll
        for (int mi = 0; mi < 4; ++mi)
#pragma unroll
            for (int ni = 0; ni < 4; ++ni)
                acc[mi][ni] = mfma16(a[mi], b[ni], acc[mi][ni]);
        __builtin_amdgcn_s_setprio(0);
        // ---- phase 2: read a4-7; issue B-stage; MFMA m4-7 x n0-3
#pragma unroll
        for (int mi = 0; mi < 4; ++mi) a[mi] = *(const s8v*)(lb + aoff[mi + 4]);
        async16(gB0 + kb, sb + 8192 + ldsA0);
        async16(gB1 + kb, sb + 8192 + ldsA1);
        __builtin_amdgcn_s_setprio(1);
#pragma unroll
        for (int mi = 0; mi < 4; ++mi)
#pragma unroll
            for (int ni = 0; ni < 4; ++ni)
                acc[mi + 4][ni] = mfma16(a[mi], b[ni], acc[mi + 4][ni]);
        __builtin_amdgcn_s_setprio(0);
    }
    asm volatile("s_waitcnt vmcnt(0)" ::: "memory");

    // ---- epilogue: region uniform per bx
    const int row0 = by * 256 + wr * 128 + q2 * 4;
    const int col0 = bx * 256 + wc * 64 + l16;
    if (bx < 12) {
        bf16* dst = (bx < 4) ? qkpre : (bx < 8 ? gate : vpre);
        const int cb = (bx < 4) ? 0 : (bx < 8 ? 1024 : 2048);
#pragma unroll
        for (int mi = 0; mi < 8; ++mi)
#pragma unroll
            for (int ni = 0; ni < 4; ++ni)
#pragma unroll
                for (int r = 0; r < 4; ++r) {
                    int row = row0 + mi * 16 + r;
                    int col = col0 + ni * 16 - cb;
                    dst[(size_t)row * 1024 + col] = f2b(acc[mi][ni][r]);
                }
    } else {
#pragma unroll
        for (int mi = 0; mi < 8; ++mi)
#pragma unroll
            for (int ni = 0; ni < 4; ++ni)
#pragma unroll
                for (int r = 0; r < 4; ++r) {
                    int row = row0 + mi * 16 + r;
                    int c = wc * 64 + ni * 16 + l16;
                    float v = acc[mi][ni][r];
                    float cl = fminf(32.f, fmaxf(-32.f, v));
                    int b_ = row >> 11, t_ = row & 2047;
                    int h_ = c >> 6, m_ = c & 63;
                    ETout[((size_t)((b_ * 4 + h_) * 64 + m_)) * 2048 + t_]
                        = f2b(expf(cl));
                }
    }
}

// ---------------------------------------------------------------------------
// conv+silu+rope for q only (pre row stride 1024, cols 0..511).
// ---------------------------------------------------------------------------
__global__ __launch_bounds__(256) void conv_q_kernel(
    const bf16* __restrict__ pre, const bf16* __restrict__ w,
    bf16* __restrict__ out)
{
    int gid = blockIdx.x * 256 + threadIdx.x;  // B*T*H*64
    int d = gid & 63;
    int h = (gid >> 6) & 3;
    int t = (gid >> 8) & 2047;
    int b = gid >> 19;
    int clo = h * HKn + d, chi = clo + 64;
    float ylo = 0.f, yhi = 0.f;
#pragma unroll
    for (int j = 0; j < 4; j++) {
        int tt = t - 3 + j;
        if (tt >= 0) {
            size_t rb = (size_t)(b * Tn + tt) * 1024;
            ylo += b2f(pre[rb + clo]) * b2f(w[clo * 4 + j]);
            yhi += b2f(pre[rb + chi]) * b2f(w[chi * 4 + j]);
        }
    }
    ylo = ylo / (1.f + expf(-ylo));
    yhi = yhi / (1.f + expf(-yhi));
    float invf = powf(10000.f, -(float)d * (1.f / 64.f));
    float th = (float)t * invf;
    float c = cosf(th), s = sinf(th);
    size_t rowbase = (size_t)(b * Tn + t) * KDn;
    out[rowbase + clo] = f2b(ylo * c - yhi * s);
    out[rowbase + chi] = f2b(yhi * c + ylo * s);
}

// ---------------------------------------------------------------------------
// conv+silu+rope for k, output TRANSPOSED: KT[(b*4+h)*128 + d][t].
// ---------------------------------------------------------------------------
__global__ __launch_bounds__(256) void conv_k_t_kernel(
    const bf16* __restrict__ pre, const bf16* __restrict__ w,
    bf16* __restrict__ KT)
{
    __shared__ bf16 tile[128 * 72];
    const int b = blockIdx.z, h = blockIdx.y, tt = blockIdx.x;
    const int tid = threadIdx.x;
    const int dp = tid >> 2, tq = tid & 3;
    const int clo = 512 + h * 128 + dp, chi = clo + 64;
    const float w0l = b2f(w[(h * 128 + dp) * 4 + 0]), w1l = b2f(w[(h * 128 + dp) * 4 + 1]),
                w2l = b2f(w[(h * 128 + dp) * 4 + 2]), w3l = b2f(w[(h * 128 + dp) * 4 + 3]);
    const float w0h = b2f(w[(h * 128 + dp + 64) * 4 + 0]), w1h = b2f(w[(h * 128 + dp + 64) * 4 + 1]),
                w2h = b2f(w[(h * 128 + dp + 64) * 4 + 2]), w3h = b2f(w[(h * 128 + dp + 64) * 4 + 3]);
    const float invf = powf(10000.f, -(float)dp * (1.f / 64.f));
    float l0 = 0.f, l1 = 0.f, l2 = 0.f, h0 = 0.f, h1 = 0.f, h2 = 0.f;
    int tg0 = tt * 64 + tq * 16;
#pragma unroll
    for (int p = 0; p < 3; p++) {
        int tg = tg0 - 3 + p;
        float xl = 0.f, xh = 0.f;
        if (tg >= 0) {
            size_t rb = (size_t)(b * Tn + tg) * 1024;
            xl = b2f(pre[rb + clo]);
            xh = b2f(pre[rb + chi]);
        }
        l0 = l1; l1 = l2; l2 = xl;
        h0 = h1; h1 = h2; h2 = xh;
    }
    for (int i = 0; i < 16; i++) {
        int tg = tg0 + i;
        size_t rb = (size_t)(b * Tn + tg) * 1024;
        float xl = b2f(pre[rb + clo]);
        float xh = b2f(pre[rb + chi]);
        float ylo = l0 * w0l + l1 * w1l + l2 * w2l + xl * w3l;
        float yhi = h0 * w0h + h1 * w1h + h2 * w2h + xh * w3h;
        l0 = l1; l1 = l2; l2 = xl;
        h0 = h1; h1 = h2; h2 = xh;
        ylo = ylo / (1.f + expf(-ylo));
        yhi = yhi / (1.f + expf(-yhi));
        float th = (float)tg * invf;
        float c = cosf(th), s = sinf(th);
        int tl = tq * 16 + i;
        tile[dp * 72 + tl] = f2b(ylo * c - yhi * s);
        tile[(dp + 64) * 72 + tl] = f2b(yhi * c + ylo * s);
    }
    __syncthreads();
#pragma unroll
    for (int c = 0; c < 4; c++) {
        int idx = c * 256 + tid;
        int ch = idx >> 3, t8 = (idx & 7) * 8;
        s8v v = *(s8v*)&tile[ch * 72 + t8];
        *(s8v*)&KT[((size_t)((b * 4 + h) * 128 + ch)) * 2048 + tt * 64 + t8] = v;
    }
}

// ---------------------------------------------------------------------------
// conv + silu for v -> VT[b*1024 + c][t].
// ---------------------------------------------------------------------------
__global__ __launch_bounds__(256) void conv_v_t_kernel(
    const bf16* __restrict__ pre, const bf16* __restrict__ w,
    bf16* __restrict__ VT)
{
    __shared__ bf16 tile[64 * 72];
    int c0 = blockIdx.x * 64, t0 = blockIdx.y * 64, b = blockIdx.z;
    int tid = threadIdx.x;
    int row = tid >> 2, seg = (tid & 3) * 16;
    float y[16];
#pragma unroll
    for (int i = 0; i < 16; i++) y[i] = 0.f;
#pragma unroll
    for (int j = 0; j < 4; j++) {
        int tt = t0 + row - 3 + j;
        if (tt >= 0) {
            const bf16* p = &pre[(size_t)(b * Tn + tt) * VDn + c0 + seg];
#pragma unroll
            for (int i = 0; i < 16; i++)
                y[i] += b2f(p[i]) * b2f(w[(c0 + seg + i) * 4 + j]);
        }
    }
#pragma unroll
    for (int i = 0; i < 16; i++) {
        float v = y[i] / (1.f + expf(-y[i]));
        tile[row * 72 + seg + i] = f2b(v);
    }
    __syncthreads();
    bf16 tmp[16];
#pragma unroll
    for (int i = 0; i < 16; i++) tmp[i] = tile[(seg + i) * 72 + row];
    size_t o = (size_t)(b * 1024 + c0 + row) * 2048 + t0 + seg;
    *(s8v*)&VT[o] = *(s8v*)&tmp[0];
    *(s8v*)&VT[o + 8] = *(s8v*)&tmp[8];
}

// ---------------------------------------------------------------------------
// cumsum checkpoints: Ccp[(b*32+j)*256 + hm] = sum of E over tiles < j.
// ---------------------------------------------------------------------------
__global__ __launch_bounds__(256) void cumsum_ccp_kernel(
    const bf16* __restrict__ ET, float* __restrict__ Ccp)
{
    int row = blockIdx.x * 4 + (threadIdx.x >> 6);   // 1024 rows = b*256 + hm
    int lane = threadIdx.x & 63;
    int b = row >> 8, hm = row & 255;
    const bf16* src = ET + (size_t)row * 2048;
    float run = 0.f;
    for (int ch = 0; ch < 32; ch++) {
        if (lane == 0) Ccp[(size_t)(b * 32 + ch) * 256 + hm] = run;
        float v = b2f(src[ch * 64 + lane]);
#pragma unroll
        for (int off = 1; off < 64; off <<= 1) {
            float o = __shfl_up(v, off, 64);
            if (lane >= off) v += o;
        }
        run += __shfl(v, 63, 64);
    }
}

// ---------------------------------------------------------------------------
// Phase A: per-tile state products (independent blocks, high occupancy).
// blocks [0,512): Sv tiles Tv_j[v=256][m=64] = V_j^T E_j  (bh = bx>>5, j = bx&31)
// blocks [512,1024): H tiles Th_j[m=64][k=128] = E_j^T K_j
// ---------------------------------------------------------------------------
__global__ __launch_bounds__(256) void tile_state_kernel(
    const bf16* __restrict__ ET, const bf16* __restrict__ KT,
    const bf16* __restrict__ VT,
    bf16* __restrict__ Svp, bf16* __restrict__ HpA, bf16* __restrict__ HpB)
{
    const int tid = threadIdx.x;
    const int w = tid >> 6, lane = tid & 63;
    const int l16 = lane & 15, q = lane >> 4;
    f4v z = {0.f, 0.f, 0.f, 0.f};
    if (blockIdx.x < 512) {
        const int bh = blockIdx.x >> 5, j = blockIdx.x & 31;
        const int b = bh >> 2, h = bh & 3;
        const int j64 = j * 64;
        f4v acc[4][4];
#pragma unroll
        for (int i = 0; i < 4; i++)
#pragma unroll
            for (int jj = 0; jj < 4; jj++) acc[i][jj] = z;
#pragma unroll
        for (int kc = 0; kc < 2; kc++) {
            s8v va[4], eb[4];
#pragma unroll
            for (int vf = 0; vf < 4; vf++)
                va[vf] = *(const s8v*)(VT + (size_t)(b * 1024 + h * 256 + w * 64 + vf * 16 + l16) * 2048
                                       + j64 + kc * 32 + q * 8);
#pragma unroll
            for (int mf = 0; mf < 4; mf++)
                eb[mf] = *(const s8v*)(ET + (size_t)(bh * 64 + mf * 16 + l16) * 2048
                                       + j64 + kc * 32 + q * 8);
#pragma unroll
            for (int vf = 0; vf < 4; vf++)
#pragma unroll
                for (int mf = 0; mf < 4; mf++)
                    acc[vf][mf] = mfma16(va[vf], eb[mf], acc[vf][mf]);
        }
#pragma unroll
        for (int vf = 0; vf < 4; vf++)
#pragma unroll
            for (int mf = 0; mf < 4; mf++)
#pragma unroll
                for (int r = 0; r < 4; r++)
                    Svp[((size_t)((bh * 32 + j) * 256 + w * 64 + vf * 16 + q * 4 + r)) * 64
                        + mf * 16 + l16] = f2b(acc[vf][mf][r]);
    } else {
        const int idx = blockIdx.x - 512;
        const int bh = idx >> 5, j = idx & 31;
        const int j64 = j * 64;
        bf16* hp = (bh < 12) ? (HpA + (size_t)bh * 262144)
                             : (HpB + (size_t)(bh - 12) * 262144);
        f4v acc[8];
#pragma unroll
        for (int i = 0; i < 8; i++) acc[i] = z;
#pragma unroll
        for (int kc = 0; kc < 2; kc++) {
            s8v ea = *(const s8v*)(ET + (size_t)(bh * 64 + w * 16 + l16) * 2048
                                   + j64 + kc * 32 + q * 8);
#pragma unroll
            for (int kf = 0; kf < 8; kf++) {
                s8v kb = *(const s8v*)(KT + (size_t)(bh * 128 + kf * 16 + l16) * 2048
                                       + j64 + kc * 32 + q * 8);
                acc[kf] = mfma16(ea, kb, acc[kf]);
            }
        }
#pragma unroll
        for (int kf = 0; kf < 8; kf++)
#pragma unroll
            for (int r = 0; r < 4; r++)
                hp[((size_t)(j64 + w * 16 + q * 4 + r)) * 128 + kf * 16 + l16]
                    = f2b(acc[kf][r]);
    }
}

// ---------------------------------------------------------------------------
// Phase B: in-place exclusive prefix over j (fp32 accumulation, bf16 storage).
// blocks [0,1024): Sv (thread per (bh, v*64+m)); [1024,1536): H (per (bh, m*128+k)).
// ---------------------------------------------------------------------------
__global__ __launch_bounds__(256) void prefix_state_kernel(
    bf16* __restrict__ Svp, bf16* __restrict__ HpA, bf16* __restrict__ HpB)
{
    if (blockIdx.x < 1024) {
        int gid = blockIdx.x * 256 + threadIdx.x;
        int bh = gid >> 14, e = gid & 16383;
        bf16* p = Svp + (size_t)bh * 524288 + e;
        float run = 0.f;
#pragma unroll 4
        for (int j = 0; j < 32; j++) {
            float x = b2f(p[(size_t)j * 16384]);
            p[(size_t)j * 16384] = f2b(run);
            run += x;
        }
    } else {
        int gid = (blockIdx.x - 1024) * 256 + threadIdx.x;
        int bh = gid >> 13, e = gid & 8191;
        bf16* hp = ((bh < 12) ? (HpA + (size_t)bh * 262144)
                              : (HpB + (size_t)(bh - 12) * 262144)) + e;
        float run = 0.f;
#pragma unroll 4
        for (int j = 0; j < 32; j++) {
            float x = b2f(hp[(size_t)j * 8192]);
            hp[(size_t)j * 8192] = f2b(run);
            run += x;
        }
    }
}

// ---------------------------------------------------------------------------
// Fused attention (unchanged).
// ---------------------------------------------------------------------------
__global__ __launch_bounds__(256) void attn12_mfma(
    const bf16* __restrict__ Q, const bf16* __restrict__ KT,
    const bf16* __restrict__ ET, const float* __restrict__ Ccp,
    const bf16* __restrict__ HpA, const bf16* __restrict__ HpB,
    const bf16* __restrict__ Svp, const bf16* __restrict__ VT,
    const bf16* __restrict__ gate, const bf16* __restrict__ gn,
    bf16* __restrict__ OV)
{
    __shared__ char smem[53760];
    bf16*  Kloc = (bf16*)smem;
    float* Ot   = (float*)smem;
    bf16*  Sl   = (bf16*)(smem + 17408);
    bf16*  Ct   = (bf16*)(smem + 17408);
    bf16*  Etl  = (bf16*)(smem + 17408);
    float* okT  = (float*)(smem + 26624);
    bf16*  Pl   = (bf16*)(smem + 26624);
    bf16*  Ul   = (bf16*)(smem + 43264);
    float* swave= (float*)(smem + 52480);
    float* ssum = (float*)(smem + 53504);
    const int tid = threadIdx.x;
    const int w = tid >> 6, lane = tid & 63;
    const int l16 = lane & 15, q = lane >> 4;
    const int bh = blockIdx.x, b = bh >> 2, h = bh & 3;
    const int j = blockIdx.y, j64 = j * 64;
    f4v z = {0.f, 0.f, 0.f, 0.f};
    const bf16* hp = (bh < 12) ? (HpA + (size_t)bh * 262144)
                               : (HpB + (size_t)(bh - 12) * 262144);

#pragma unroll
    for (int c = 0; c < 4; c++) {
        int idx = c * 256 + tid;
        int kr = idx >> 3, t8 = (idx & 7) * 8;
        alignas(16) bf16 tmp[8];
        *(s8v*)tmp = *(const s8v*)&KT[((size_t)(bh * 128 + kr)) * 2048 + j64 + t8];
#pragma unroll
        for (int i = 0; i < 8; i++) Kloc[(t8 + i) * 136 + kr] = tmp[i];
    }
    const bf16* qrow = Q + (size_t)(b * 2048 + j64 + w * 16 + l16) * 512 + h * 128;
    s8v qa[4];
#pragma unroll
    for (int kc = 0; kc < 4; kc++) qa[kc] = *(const s8v*)(qrow + kc * 32 + q * 8);
    __syncthreads();
    {
        f4v sT[4];
#pragma unroll
        for (int fi = 0; fi < 4; fi++) sT[fi] = z;
#pragma unroll
        for (int kc = 0; kc < 4; kc++)
#pragma unroll
            for (int fi = 0; fi < 4; fi++) {
                s8v kb = *(s8v*)&Kloc[(fi * 16 + l16) * 136 + kc * 32 + q * 8];
                sT[fi] = mfma16(kb, qa[kc], sT[fi]);
            }
        const int tl = w * 16 + l16;
#pragma unroll
        for (int fi = 0; fi < 4; fi++) {
            alignas(8) bf16 pk[4];
#pragma unroll
            for (int r = 0; r < 4; r++) {
                int taul = fi * 16 + q * 4 + r;
                pk[r] = (taul <= tl) ? f2b(sT[fi][r]) : f2b(0.f);
            }
            *(s4v*)&Sl[tl * 72 + fi * 16 + q * 4] = *(s4v*)pk;
        }
    }
    __syncthreads();
    {
        f4v ok[4];
#pragma unroll
        for (int i = 0; i < 4; i++) ok[i] = z;
        const bf16* etrow = ET + (size_t)(bh * 64 + w * 16 + l16) * 2048 + j64;
#pragma unroll
        for (int kc = 0; kc < 2; kc++) {
            s8v ea = *(const s8v*)(etrow + kc * 32 + q * 8);
#pragma unroll
            for (int tf = 0; tf < 4; tf++) {
                s8v sb = *(s8v*)&Sl[(tf * 16 + l16) * 72 + kc * 32 + q * 8];
                ok[tf] = mfma16(ea, sb, ok[tf]);
            }
        }
        const bf16* hrow = hp + (size_t)(j64 + w * 16 + l16) * 128;
#pragma unroll
        for (int kc = 0; kc < 4; kc++) {
            s8v ha = *(const s8v*)(hrow + kc * 32 + q * 8);
#pragma unroll
            for (int tf = 0; tf < 4; tf++) {
                s8v qb = *(const s8v*)(Q + (size_t)(b * 2048 + j64 + tf * 16 + l16) * 512
                                       + h * 128 + kc * 32 + q * 8);
                ok[tf] = mfma16(ha, qb, ok[tf]);
            }
        }
#pragma unroll
        for (int tf = 0; tf < 4; tf++)
#pragma unroll
            for (int r = 0; r < 4; r++)
                okT[(w * 16 + q * 4 + r) * 65 + tf * 16 + l16] = ok[tf][r];
    }
    __syncthreads();
    for (int mi = 0; mi < 16; mi++) {
        int m = w * 16 + mi;
        float v = b2f(ET[(size_t)(bh * 64 + m) * 2048 + j64 + lane]);
#pragma unroll
        for (int off = 1; off < 64; off <<= 1) {
            float o = __shfl_up(v, off, 64);
            if (lane >= off) v += o;
        }
        float c0 = Ccp[(size_t)(b * 32 + j) * 256 + h * 64 + m];
        Ct[m * 72 + lane] = f2b(c0 + v);
    }
    __syncthreads();
    if (tid < 64) {
        const int t = tid;
        const float scale = 0.08838834764831845f;
        float mx = -1e30f;
        for (int m = 0; m < 64; m++) {
            float c = b2f(Ct[m * 72 + t]);
            float v = okT[m * 65 + t] * scale / c;
            okT[m * 65 + t] = v;
            mx = fmaxf(mx, v);
        }
        float sum = 0.f;
        for (int m = 0; m < 64; m++) {
            float e = expf(okT[m * 65 + t] - mx);
            okT[m * 65 + t] = e;
            sum += e;
        }
        float inv = 1.f / sum;
        for (int m = 0; m < 64; m++) {
            float c = b2f(Ct[m * 72 + t]);
            Ul[t * 72 + m] = f2b(okT[m * 65 + t] * inv / c);
        }
    }
    __syncthreads();
#pragma unroll
    for (int c = 0; c < 2; c++) {
        int idx = c * 256 + tid;
        int mr = idx >> 3, t8 = (idx & 7) * 8;
        alignas(16) bf16 tmp[8];
        *(s8v*)tmp = *(const s8v*)&ET[(size_t)(bh * 64 + mr) * 2048 + j64 + t8];
#pragma unroll
        for (int i = 0; i < 8; i++) Etl[(t8 + i) * 72 + mr] = tmp[i];
    }
    __syncthreads();
    {
        s8v ub[2];
#pragma unroll
        for (int kc = 0; kc < 2; kc++)
            ub[kc] = *(s8v*)&Ul[(w * 16 + l16) * 72 + kc * 32 + q * 8];
        f4v pT[4];
#pragma unroll
        for (int fi = 0; fi < 4; fi++) pT[fi] = z;
#pragma unroll
        for (int kc = 0; kc < 2; kc++)
#pragma unroll
            for (int fi = 0; fi < 4; fi++) {
                s8v eb = *(s8v*)&Etl[(fi * 16 + l16) * 72 + kc * 32 + q * 8];
                pT[fi] = mfma16(eb, ub[kc], pT[fi]);
            }
        const int tl = w * 16 + l16;
#pragma unroll
        for (int fi = 0; fi < 4; fi++) {
            alignas(8) bf16 pk[4];
#pragma unroll
            for (int r = 0; r < 4; r++) {
                int taul = fi * 16 + q * 4 + r;
                pk[r] = (taul <= tl) ? f2b(pT[fi][r]) : f2b(0.f);
            }
            *(s4v*)&Pl[tl * 72 + fi * 16 + q * 4] = *(s4v*)pk;
        }
    }
    __syncthreads();
    f4v oacc[4][4];
#pragma unroll
    for (int zc = 0; zc < 4; zc++)
#pragma unroll
        for (int i = 0; i < 4; i++) oacc[zc][i] = z;
    {
        const bf16* vtrow = VT + (size_t)(b * 1024 + h * 256 + w * 16 + l16) * 2048 + j64;
        const bf16* svrow = Svp + (size_t)((bh * 32 + j) * 256 + w * 16 + l16) * 64;
#pragma unroll
        for (int kc = 0; kc < 2; kc++) {
            s8v pb[4], ub2[4];
#pragma unroll
            for (int tf = 0; tf < 4; tf++) {
                pb[tf] = *(s8v*)&Pl[(tf * 16 + l16) * 72 + kc * 32 + q * 8];
                ub2[tf] = *(s8v*)&Ul[(tf * 16 + l16) * 72 + kc * 32 + q * 8];
            }
#pragma unroll
            for (int zc = 0; zc < 4; zc++) {
                s8v vt = *(const s8v*)(vtrow + (size_t)(zc * 64) * 2048 + kc * 32 + q * 8);
                s8v sv = *(const s8v*)(svrow + (size_t)(zc * 64) * 64 + kc * 32 + q * 8);
#pragma unroll
                for (int tf = 0; tf < 4; tf++) {
                    oacc[zc][tf] = mfma16(vt, pb[tf], oacc[zc][tf]);
                    oacc[zc][tf] = mfma16(sv, ub2[tf], oacc[zc][tf]);
                }
            }
        }
    }
    float part[4] = {0.f, 0.f, 0.f, 0.f};
#pragma unroll
    for (int zc = 0; zc < 4; zc++)
#pragma unroll
        for (int tf = 0; tf < 4; tf++)
#pragma unroll
            for (int r = 0; r < 4; r++)
                part[tf] += oacc[zc][tf][r] * oacc[zc][tf][r];
#pragma unroll
    for (int tf = 0; tf < 4; tf++) {
        part[tf] += __shfl_xor(part[tf], 16, 64);
        part[tf] += __shfl_xor(part[tf], 32, 64);
    }
    if (q == 0) {
#pragma unroll
        for (int tf = 0; tf < 4; tf++) swave[w * 64 + tf * 16 + l16] = part[tf];
    }
    const int trow = tid >> 2, vseg = (tid & 3) * 16;
    for (int zc = 0; zc < 4; zc++) {
#pragma unroll
        for (int tf = 0; tf < 4; tf++)
            *(f4v*)&Ot[(tf * 16 + l16) * 68 + w * 16 + q * 4] = oacc[zc][tf];
        __syncthreads();
        if (zc == 0) {
            if (tid < 64)
                ssum[tid] = rsqrtf((swave[tid] + swave[64 + tid] + swave[128 + tid]
                                    + swave[192 + tid]) * (1.0f / 256.0f) + 1e-5f);
            __syncthreads();
        }
        float rs = ssum[trow];
        size_t orow = (size_t)(b * 2048 + j64 + trow) * 1024 + h * 256 + zc * 64 + vseg;
        alignas(16) bf16 gh[16];
        *(s8v*)&gh[0] = *(const s8v*)&gate[orow];
        *(s8v*)&gh[8] = *(const s8v*)&gate[orow + 8];
        alignas(16) bf16 tmp[16];
#pragma unroll
        for (int i = 0; i < 16; i++) {
            float g = b2f(gh[i]);
            float sg = g / (1.f + expf(-g));
            float val = Ot[trow * 68 + vseg + i] * rs * b2f(gn[zc * 64 + vseg + i]) * sg;
            tmp[i] = f2b(val);
        }
        *(s8v*)&OV[orow] = *(s8v*)&tmp[0];
        *(s8v*)&OV[orow + 8] = *(s8v*)&tmp[8];
        __syncthreads();
    }
}

// ---------------------------------------------------------------------------
extern "C" void kernel_launch(void* const* d_in, const int* in_sizes, int n_in,
                              void* d_out, int out_size, void* d_ws, size_t ws_size,
                              hipStream_t stream)
{
    constexpr size_t MB = 1u << 20;
    char* w = (char*)d_ws;
    bf16* Xb   = (bf16*)(w + 0);                 // [0,16) -> OV after merged GEMM
    bf16* OVb  = (bf16*)(w + 0);
    bf16* WoT  = (bf16*)(w + 16 * MB);           // [16,18)
    bf16* WallT= (bf16*)(w + 18 * MB);           // [18,24.5): WqkT|WgT|WvT|WsT
    bf16* WkT  = (bf16*)(w + 19 * MB);
    bf16* WgT  = (bf16*)(w + 20 * MB);
    bf16* WvT  = (bf16*)(w + 22 * MB);
    bf16* WsT  = (bf16*)(w + 24 * MB);
    bf16* HpA  = (bf16*)(w + 18 * MB);           // [18,24) after merged GEMM
    bf16* gnwb = (bf16*)(w + 24 * MB + 524288);  // smalls [24.5,25)
    bf16* qwb  = (bf16*)(w + 24 * MB + 532480);
    bf16* kwb  = (bf16*)(w + 24 * MB + 540672);
    bf16* vwb  = (bf16*)(w + 24 * MB + 548864);
    int*  flagp= (int*) (w + 24 * MB + 565248);
    bf16* qkpre= (bf16*)(w + 25 * MB);           // [25,41) -> Svp after convs
    bf16* Svp  = (bf16*)(w + 25 * MB);
    bf16* ETb  = (bf16*)(w + 41 * MB);           // [41,45)
    bf16* vpre = (bf16*)(w + 45 * MB);           // [45,61) -> Qb/KTb after conv_v
    bf16* Qb   = (bf16*)(w + 45 * MB);           // [45,53)
    bf16* KTb  = (bf16*)(w + 53 * MB);           // [53,61)
    float* Ccp = (float*)(w + 61 * MB);          // [61,61.25)
    bf16* HpB  = (bf16*)(w + 61 * MB + 262144);  // [61.25,63.25)
    bf16* VT   = (bf16*)d_out;                   // d_out[0,16MB)
    bf16* gate = (bf16*)d_out + 8 * 1024 * 1024; // d_out[16,32MB)

    dim3 blk(256);
    probe_dtype_kernel<<<1, blk, 0, stream>>>(d_in[0], flagp);
    convert_kernel<<<16384, blk, 0, stream>>>(d_in[0], Xb, flagp, BT * Dn);
    convert_small_kernel<<<1, blk, 0, stream>>>(d_in[7], d_in[8], d_in[9], d_in[10],
                                                qwb, kwb, vwb, gnwb, flagp);
    convert_t6_kernel<<<1088, blk, 0, stream>>>(d_in[1], d_in[2], d_in[3], d_in[4],
                                                d_in[5], d_in[6],
                                                WallT, WkT, WvT, WsT, WgT, WoT, flagp);
    // ONE merged projection GEMM (256^2 tile, 4-deep pipelined):
    // N = 3328 (qk | gate | v | s->ET), grid 13x32 = 416 blocks, 512 thr.
    gemm256_mproj<<<416, dim3(512), 0, stream>>>(Xb, WallT, qkpre, ETb, gate, vpre);
    // convs: v (transposed), q, k (transposed+rope)
    conv_v_t_kernel<<<dim3(16, 32, 4), blk, 0, stream>>>(vpre, vwb, VT);
    conv_q_kernel<<<8192, blk, 0, stream>>>(qkpre, qwb, Qb);
    conv_k_t_kernel<<<dim3(32, 4, 4), blk, 0, stream>>>(qkpre, kwb, KTb);
    // per-slot scalar checkpoints
    cumsum_ccp_kernel<<<256, blk, 0, stream>>>(ETb, Ccp);
    // two-phase prefix state: independent tile products, then prefix pass
    tile_state_kernel<<<1024, blk, 0, stream>>>(ETb, KTb, VT, Svp, HpA, HpB);
    prefix_state_kernel<<<1536, blk, 0, stream>>>(Svp, HpA, HpB);
    // fused attention + norm + gate -> OV (over dead Xb)
    attn12_mfma<<<dim3(16, 32), blk, 0, stream>>>(Qb, KTb, ETb, Ccp, HpA, HpB,
                                                  Svp, VT, gate, gnwb, OVb);
    // output projection (dynamic out dtype)
    gemm_mfma<3><<<dim3(8, 64), blk, 0, stream>>>(OVb, WoT, d_out, nullptr, nullptr, nullptr,
                                                  flagp, BT, Dn, VDn);
}